// Round 6
// baseline (480.005 us; speedup 1.0000x reference)
//
#include <hip/hip_runtime.h>

#define T_TOK 4096
#define DIN   1024
#define DOUT  1024
#define NEXP  8
#define HDIM  4096
#define RCAP  9216       // 8192 rows + 8 experts x <=127 pad (128-aligned)
#define MT128 80

typedef float f32x4 __attribute__((ext_vector_type(4)));
typedef short bf16x8 __attribute__((ext_vector_type(8)));
typedef unsigned short u16x4 __attribute__((ext_vector_type(4)));

__device__ __forceinline__ float bf2f(unsigned short u) {
    union { unsigned int i; float f; } v; v.i = ((unsigned int)u) << 16; return v.f;
}
__device__ __forceinline__ unsigned short f2bf(float f) {
    union { unsigned int i; float f; } v; v.f = f;
    unsigned int r = v.i + 0x7FFFu + ((v.i >> 16) & 1u);
    return (unsigned short)(r >> 16);
}

__global__ void init_kernel(int* cnt) {
    if (threadIdx.x < NEXP) cnt[threadIdx.x] = 0;
}

// One wave per token: fp64 gating dots, softplus, top-2, softmax, routing.
__global__ __launch_bounds__(64) void gating_kernel(
    const float* __restrict__ x, const float* __restrict__ noise,
    const float* __restrict__ gw, const float* __restrict__ gb,
    const float* __restrict__ nw, const float* __restrict__ nb,
    float* __restrict__ wout, int* __restrict__ cnt,
    int* __restrict__ tok_e, int* __restrict__ tok_slot, float* __restrict__ tok_p)
{
    int t = blockIdx.x;
    int lane = threadIdx.x;
    const float* xr = x + (size_t)t * DIN;
    double ag[NEXP], an[NEXP];
#pragma unroll
    for (int e = 0; e < NEXP; ++e) { ag[e] = 0.0; an[e] = 0.0; }
    for (int d = lane; d < DIN; d += 64) {
        double xv = (double)xr[d];
        const f32x4* g4 = (const f32x4*)(gw + (size_t)d * NEXP);
        const f32x4* n4 = (const f32x4*)(nw + (size_t)d * NEXP);
        f32x4 ga = g4[0], gbv = g4[1], na = n4[0], nbv = n4[1];
#pragma unroll
        for (int j = 0; j < 4; ++j) {
            ag[j]     += xv * (double)ga[j];
            ag[4 + j] += xv * (double)gbv[j];
            an[j]     += xv * (double)na[j];
            an[4 + j] += xv * (double)nbv[j];
        }
    }
#pragma unroll
    for (int e = 0; e < NEXP; ++e) {
        double g = ag[e], n = an[e];
#pragma unroll
        for (int m = 32; m > 0; m >>= 1) { g += __shfl_xor(g, m); n += __shfl_xor(n, m); }
        ag[e] = g; an[e] = n;
    }
    double lg[NEXP];
#pragma unroll
    for (int e = 0; e < NEXP; ++e) {
        double z = an[e] + (double)nb[e];
        double sp = fmax(z, 0.0) + log1p(exp(-fabs(z)));
        lg[e] = ag[e] + (double)gb[e] + (double)noise[(size_t)t * NEXP + e] * sp;
    }
    int i0 = 0; double v0 = lg[0];
#pragma unroll
    for (int e = 1; e < NEXP; ++e) if (lg[e] > v0) { v0 = lg[e]; i0 = e; }
    int i1 = -1; double v1 = -1.0e300;
#pragma unroll
    for (int e = 0; e < NEXP; ++e) if (e != i0 && lg[e] > v1) { v1 = lg[e]; i1 = e; }
    double d1 = exp(v1 - v0);
    float p0 = (float)(1.0 / (1.0 + d1));
    float p1 = (float)(d1 / (1.0 + d1));
    if (lane < NEXP) {
        float wv = (lane == i0) ? p0 : ((lane == i1) ? p1 : 0.0f);
        wout[(size_t)t * NEXP + lane] = wv;
    }
    if (lane == 0) {
        int s0 = atomicAdd(&cnt[i0], 1);
        int s1 = atomicAdd(&cnt[i1], 1);
        tok_e[2 * t] = i0;     tok_e[2 * t + 1] = i1;
        tok_slot[2 * t] = s0;  tok_slot[2 * t + 1] = s1;
        tok_p[2 * t] = p0;     tok_p[2 * t + 1] = p1;
    }
}

// 128-row-aligned per-expert offsets + 128-row tile map.
__global__ void prefix_kernel(const int* __restrict__ cnt, int* __restrict__ poff,
                              int* __restrict__ t2e, int* __restrict__ trow)
{
    if (threadIdx.x != 0 || blockIdx.x != 0) return;
    int base = 0, a = 0;
    for (int e = 0; e < NEXP; ++e) {
        poff[e] = base;
        int c = cnt[e];
        int nt = (c + 127) >> 7;
        for (int i = 0; i < nt; ++i) { t2e[a] = e; trow[a] = base + (i << 7); ++a; }
        base += nt << 7;
    }
    for (; a < MT128; ++a) { t2e[a] = -1; trow[a] = 0; }
}

// Copy token row t (fp32) to its expert slot as bf16.
__global__ __launch_bounds__(256) void gather_kernel(
    const float* __restrict__ x, const int* __restrict__ tok_e,
    const int* __restrict__ tok_slot, const int* __restrict__ poff,
    unsigned short* __restrict__ Xg)
{
    int b = blockIdx.x;
    int t = b >> 1, k = b & 1;
    int e = tok_e[2 * t + k];
    int row = poff[e] + tok_slot[2 * t + k];
    int c = threadIdx.x << 2;
    f32x4 v = *(const f32x4*)(x + (size_t)t * DIN + c);
    u16x4 o;
#pragma unroll
    for (int j = 0; j < 4; ++j) o[j] = f2bf(v[j]);
    *(u16x4*)(Xg + (size_t)row * DIN + c) = o;
}

// Transpose+convert: W [E][K][N] fp32 -> Wt [E][N][K] bf16 (64x64 LDS tiles).
__global__ __launch_bounds__(256) void convw_kernel(
    const float* __restrict__ W, unsigned short* __restrict__ Wt, int K, int N)
{
    __shared__ float tile[64][65];
    int e = blockIdx.x;
    int k0 = blockIdx.y << 6;
    int n0 = blockIdx.z << 6;
    int tid = threadIdx.x;
    const float* src = W + ((size_t)e * K + k0) * N + n0;
    int r = tid >> 4, c4 = (tid & 15) << 2;
#pragma unroll
    for (int i = 0; i < 4; ++i) {
        f32x4 v = *(const f32x4*)(src + (size_t)(r + (i << 4)) * N + c4);
        *(f32x4*)(&tile[r + (i << 4)][c4]) = v;
    }
    __syncthreads();
    unsigned short* dst = Wt + ((size_t)e * N + n0) * K + k0;
    int n = tid >> 2, kq = (tid & 3) << 4;
#pragma unroll
    for (int j = 0; j < 4; ++j) {
        int kk = kq + (j << 2);
        u16x4 o;
#pragma unroll
        for (int q = 0; q < 4; ++q) o[q] = f2bf(tile[kk + q][n]);
        *(u16x4*)(dst + (size_t)n * K + kk) = o;
    }
}

// Unified 128x128 GEMM, BK=32, 4 waves, 3-buffer LDS ring (48 KB -> 3 blk/CU),
// ONE s_barrier + counted vmcnt(4) per K-step, proven zero-conflict swizzle,
// XCD-chunked decode, optional split-K (ks selects C + K-offset; ks=1 no bias).
// Hazard ledger (per wave, 4 gload_lds per tile):
//   prologue: stage t0,t1 (8 loads) -> vmcnt(4) = t0 resident, t1 in flight.
//   step t: barrier; stage t+2 into ring (t+2)%3; ds_read ring t%3;
//           vmcnt(4) retires t+1 (its loads are the 4 oldest); MFMA.
//   WAR: stage target (t+2)%3 == (t-1)%3 was ds_read in step t-1; each wave's
//        step-(t-1) reads complete before its MFMA issues (register deps),
//        which precedes its step-t barrier arrival; sched_barrier(0) pins the
//        MFMA (register-only, else hoistable per ERRATA#18) before the barrier.
//   RAW: ring t%3 staged at t-2, retired by every wave's vmcnt(4) at t-1
//        before its step-t barrier. Tail: vmcnt(0).
__global__ __launch_bounds__(256, 2) void gemm_ring_kernel(
    const unsigned short* __restrict__ A, int lda,
    const unsigned short* __restrict__ Bt, int ldb, int N, int KLEN,
    unsigned short* __restrict__ C0, unsigned short* __restrict__ C1,
    const float* __restrict__ bias,
    const int* __restrict__ t2e, const int* __restrict__ trow,
    int nbshift, int ksplit, int relu)
{
    int nwg = gridDim.x;
    int cpx = nwg >> 3;
    int wg = ((blockIdx.x & 7) * cpx) + (blockIdx.x >> 3);
    int tileid = wg >> (nbshift + ksplit);
    int low = wg & ((1 << (nbshift + ksplit)) - 1);
    int nb = low >> ksplit;
    int ks = ksplit ? (low & 1) : 0;

    int e = t2e[tileid];
    if (e < 0) return;
    int row0 = trow[tileid];
    int n0 = nb << 7;
    int koff = ks * KLEN;
    unsigned short* C = ks ? C1 : C0;

    __shared__ __align__(16) unsigned short lds[3 * 8192];   // ring of 3 x (A 8KB | B 8KB)

    int tid = threadIdx.x;
    int lane = tid & 63;
    int wv = tid >> 6;
    int wr = (wv >> 1) << 6;
    int wc = (wv & 1) << 6;

    const unsigned short* Ab = A + (size_t)row0 * lda + koff;
    const unsigned short* Bb = Bt + ((size_t)e * N + n0) * ldb + koff;

    f32x4 acc[4][4] = {};

    // stage-side swizzle (source pre-swizzled, LDS dest linear)
    int srow = lane >> 2;
    int skc = (((lane & 3) ^ ((lane >> 3) & 3)) << 3);
    // read-side: same involution
    int hr = lane & 15;
    int kfrag = (((lane >> 4) ^ ((lane >> 1) & 3)) << 3);

    int NKT = KLEN >> 5;

    // prologue: stage tiles 0 and 1 into ring slots 0,1
#pragma unroll
    for (int t = 0; t < 2; ++t) {
        unsigned short* base = &lds[t * 8192];
        int kb = t << 5;
#pragma unroll
        for (int j = 0; j < 2; ++j) {
            int c = wv + (j << 2);
            int r = (c << 4) + srow;
            __builtin_amdgcn_global_load_lds(
                (const __attribute__((address_space(1))) void*)(Ab + (size_t)r * lda + kb + skc),
                (__attribute__((address_space(3))) void*)(base + (c << 9)), 16, 0, 0);
            __builtin_amdgcn_global_load_lds(
                (const __attribute__((address_space(1))) void*)(Bb + (size_t)r * ldb + kb + skc),
                (__attribute__((address_space(3))) void*)(base + 4096 + (c << 9)), 16, 0, 0);
        }
    }
    asm volatile("s_waitcnt vmcnt(4)" ::: "memory");   // tile 0 resident

    int bt = 0, bs = 2;
    for (int kt = 0; kt < NKT; ++kt) {
        __builtin_amdgcn_sched_barrier(0);             // pin prior MFMA+waits before barrier
        asm volatile("s_barrier" ::: "memory");
        // stage tile kt+2 into ring bs
        if (kt + 2 < NKT) {
            unsigned short* sbase = &lds[bs * 8192];
            int kb2 = (kt + 2) << 5;
#pragma unroll
            for (int j = 0; j < 2; ++j) {
                int c = wv + (j << 2);
                int r = (c << 4) + srow;
                __builtin_amdgcn_global_load_lds(
                    (const __attribute__((address_space(1))) void*)(Ab + (size_t)r * lda + kb2 + skc),
                    (__attribute__((address_space(3))) void*)(sbase + (c << 9)), 16, 0, 0);
                __builtin_amdgcn_global_load_lds(
                    (const __attribute__((address_space(1))) void*)(Bb + (size_t)r * ldb + kb2 + skc),
                    (__attribute__((address_space(3))) void*)(sbase + 4096 + (c << 9)), 16, 0, 0);
            }
        }
        // fragment reads from ring bt
        const unsigned short* As = &lds[bt * 8192];
        const unsigned short* Bs = As + 4096;
        bf16x8 af[4], bfv[4];
#pragma unroll
        for (int m = 0; m < 4; ++m)
            af[m] = *(const bf16x8*)(&As[((wr + (m << 4) + hr) << 5) + kfrag]);
#pragma unroll
        for (int n = 0; n < 4; ++n)
            bfv[n] = *(const bf16x8*)(&Bs[((wc + (n << 4) + hr) << 5) + kfrag]);

        if (kt + 2 < NKT) asm volatile("s_waitcnt vmcnt(4)" ::: "memory");
        else              asm volatile("s_waitcnt vmcnt(0)" ::: "memory");

        __builtin_amdgcn_s_setprio(1);
#pragma unroll
        for (int m = 0; m < 4; ++m)
#pragma unroll
            for (int n = 0; n < 4; ++n)
                acc[m][n] = __builtin_amdgcn_mfma_f32_16x16x32_bf16(af[m], bfv[n], acc[m][n], 0, 0, 0);
        __builtin_amdgcn_s_setprio(0);

        bt = (bt == 2) ? 0 : bt + 1;
        bs = (bs == 2) ? 0 : bs + 1;
    }

    int rq = (lane >> 4) << 2;
    int cl = lane & 15;
#pragma unroll
    for (int n = 0; n < 4; ++n) {
        int col = wc + (n << 4) + cl;
        float bv = (ks == 0) ? bias[(size_t)e * N + n0 + col] : 0.0f;
#pragma unroll
        for (int m = 0; m < 4; ++m) {
#pragma unroll
            for (int r = 0; r < 4; ++r) {
                int row = wr + (m << 4) + rq + r;
                float v = acc[m][n][r] + bv;
                if (relu) v = fmaxf(v, 0.0f);
                C[(size_t)(row0 + row) * N + n0 + col] = f2bf(v);
            }
        }
    }
}

// x_out[t] = p0*(Oa[r0]+Ob[r0]) + p1*(Oa[r1]+Ob[r1])
__global__ __launch_bounds__(256) void combine_kernel(
    const unsigned short* __restrict__ Oa, const unsigned short* __restrict__ Ob,
    const int* __restrict__ tok_e, const int* __restrict__ tok_slot,
    const float* __restrict__ tok_p, const int* __restrict__ poff,
    float* __restrict__ xout)
{
    int t = blockIdx.x;
    int e0 = tok_e[2 * t], e1 = tok_e[2 * t + 1];
    int r0 = poff[e0] + tok_slot[2 * t];
    int r1 = poff[e1] + tok_slot[2 * t + 1];
    float p0 = tok_p[2 * t], p1 = tok_p[2 * t + 1];
    int c = threadIdx.x << 2;
    u16x4 a0 = *(const u16x4*)(Oa + (size_t)r0 * DOUT + c);
    u16x4 a1 = *(const u16x4*)(Ob + (size_t)r0 * DOUT + c);
    u16x4 b0 = *(const u16x4*)(Oa + (size_t)r1 * DOUT + c);
    u16x4 b1 = *(const u16x4*)(Ob + (size_t)r1 * DOUT + c);
    f32x4 r;
#pragma unroll
    for (int j = 0; j < 4; ++j)
        r[j] = p0 * (bf2f(a0[j]) + bf2f(a1[j])) + p1 * (bf2f(b0[j]) + bf2f(b1[j]));
    *(f32x4*)(xout + (size_t)t * DOUT + c) = r;
}

extern "C" void kernel_launch(void* const* d_in, const int* in_sizes, int n_in,
                              void* d_out, int out_size, void* d_ws, size_t ws_size,
                              hipStream_t stream)
{
    const float* x     = (const float*)d_in[0];
    const float* noise = (const float*)d_in[1];
    const float* gw    = (const float*)d_in[2];
    const float* gb    = (const float*)d_in[3];
    const float* nw    = (const float*)d_in[4];
    const float* nb    = (const float*)d_in[5];
    const float* w1    = (const float*)d_in[6];
    const float* b1    = (const float*)d_in[7];
    const float* w2    = (const float*)d_in[8];
    const float* b2    = (const float*)d_in[9];
    float* xout = (float*)d_out;
    float* wout = xout + (size_t)T_TOK * DOUT;

    char* ws = (char*)d_ws;
    int*   cnt      = (int*)(ws + 0);
    int*   poff     = (int*)(ws + 256);
    int*   t2e      = (int*)(ws + 512);
    int*   trow     = (int*)(ws + 1024);
    int*   tok_e    = (int*)(ws + 2048);
    int*   tok_slot = (int*)(ws + 34816);
    float* tok_p    = (float*)(ws + 67584);
    size_t oXg = 104448;                                  // 256-aligned
    unsigned short* Xg  = (unsigned short*)(ws + oXg);
    size_t oH  = oXg + (size_t)RCAP * DIN * 2;            // Xg 18.9 MB
    unsigned short* H   = (unsigned short*)(ws + oH);     // H 75.5 MB
    size_t oW1 = oH + (size_t)RCAP * HDIM * 2;
    unsigned short* W1t = (unsigned short*)(ws + oW1);    // 67.1 MB
    size_t oW2 = oW1 + (size_t)NEXP * HDIM * DIN * 2;
    unsigned short* W2t = (unsigned short*)(ws + oW2);    // 67.1 MB
    // Oa/Ob alias W1t (dead after GEMM1): 2 x 18.9 MB <= 67.1 MB
    unsigned short* Oa = W1t;
    unsigned short* Ob = W1t + (size_t)RCAP * DOUT;
    // total ~228.6 MB

    init_kernel<<<1, 64, 0, stream>>>(cnt);
    gating_kernel<<<T_TOK, 64, 0, stream>>>(x, noise, gw, gb, nw, nb,
                                            wout, cnt, tok_e, tok_slot, tok_p);
    prefix_kernel<<<1, 1, 0, stream>>>(cnt, poff, t2e, trow);
    gather_kernel<<<2 * T_TOK, 256, 0, stream>>>(x, tok_e, tok_slot, poff, Xg);
    convw_kernel<<<dim3(NEXP, DIN / 64, HDIM / 64), 256, 0, stream>>>(w1, W1t, DIN, HDIM);
    convw_kernel<<<dim3(NEXP, HDIM / 64, DOUT / 64), 256, 0, stream>>>(w2, W2t, HDIM, DOUT);
    // GEMM1: H = relu(Xg @ W1[e] + b1): 80 tiles x 32 n-blocks
    gemm_ring_kernel<<<MT128 * 32, 256, 0, stream>>>(
        Xg, DIN, W1t, DIN, HDIM, DIN, H, H, b1, t2e, trow, 5, 0, 1);
    // GEMM2 split-K=2: Oa = H[:,:2048] @ W2[...,:2048] + b2 ; Ob = second half (no bias)
    gemm_ring_kernel<<<MT128 * 8 * 2, 256, 0, stream>>>(
        H, HDIM, W2t, HDIM, DOUT, HDIM / 2, Oa, Ob, b2, t2e, trow, 3, 1, 0);
    combine_kernel<<<T_TOK, 256, 0, stream>>>(Oa, Ob, tok_e, tok_slot, tok_p, poff, xout);
}